// Round 9
// baseline (214.666 us; speedup 1.0000x reference)
//
#include <hip/hip_runtime.h>
#include <hip/hip_bf16.h>
#include <string.h>

#define NE 1000000
#define NN 100000
#define NWT 31250    // edges / 32 per wave-tile
#define NGT 6250     // nodes / 16 per node-group

typedef __attribute__((ext_vector_type(8))) short bf16x8;
typedef __attribute__((ext_vector_type(4))) float f32x4;

__device__ __forceinline__ unsigned short f2bf(float f) {
  // round-to-nearest-even f32 -> bf16 (prep only)
  unsigned u = __builtin_bit_cast(unsigned, f);
  u += 0x7fffu + ((u >> 16) & 1u);
  return (unsigned short)(u >> 16);
}
// packed pair: low16 = bf16(a), high16 = bf16(b)  (v_cvt_pk_bf16_f32)
__device__ __forceinline__ unsigned pk2(float a, float b) {
  __hip_bfloat162 h = __float22bfloat162_rn(make_float2(a, b));
  unsigned r;
  memcpy(&r, &h, 4);  // __hip_bfloat162 not trivially copyable -> no bit_cast
  return r;
}
__device__ __forceinline__ float lo2f(unsigned u) {
  return __builtin_bit_cast(float, u << 16);
}
__device__ __forceinline__ float hi2f(unsigned u) {
  return __builtin_bit_cast(float, u & 0xffff0000u);
}

// ---------------------------------------------------------------------------
// Prep: MFMA fragments for Wcat^T (A-operand of node_gemm) and W2 (B-operand
// of edge kernel). Wcat = [W1a | W1b] : [128][256].
// A-frag(mt,kb): lane l, j: Wcat[kb*32+(l>>4)*8+j][mt*16+(l&15)]  (16 mt, 4 kb)
// B-frag(nt,kb): lane l, j: W2[kb*32+(l>>4)*8+j][nt*16+(l&15)]    (4 nt, 4 kb)
// ---------------------------------------------------------------------------
__global__ void prep(const float* __restrict__ W1, const float* __restrict__ W2,
                     unsigned short* __restrict__ afw, unsigned short* __restrict__ fw2) {
  int tid = blockIdx.x * 256 + threadIdx.x;
  if (tid < 32768) {
    int j = tid & 7, l = (tid >> 3) & 63, kb = (tid >> 9) & 3, mt = tid >> 11;
    int k = kb * 32 + (l >> 4) * 8 + j;   // 0..127
    int n = mt * 16 + (l & 15);           // 0..255
    float v = (n < 128) ? W1[k * 128 + n] : W1[(128 + k) * 128 + (n - 128)];
    afw[tid] = f2bf(v);
  } else if (tid < 40960) {
    int t = tid - 32768;
    int j = t & 7, l = (t >> 3) & 63, kb = (t >> 9) & 3, nt = t >> 11;
    fw2[t] = f2bf(W2[(kb * 32 + (l >> 4) * 8 + j) * 64 + nt * 16 + (l & 15)]);
  }
}

// ---------------------------------------------------------------------------
// node_gemm v3 — feature-split waves. Each wave: 16 nodes x 128 features
// (half of the 256 output features). acc = 8 x f32x4 = 32 VGPR -> fits
// (256,4) = 16 waves/CU. NO LDS, NO barrier: afw half (32 KB) re-read from
// L1/L2 (64 KB total working set, shared by all blocks). Block of 4 waves =
// 2 node-groups x 2 feature-halves; same-block waves share z rows via L1.
// z converted to bf16 at load (16 VGPR payload). D layout: lane holds 4
// consecutive features of one node -> packed 8 B bf16 store.
// ---------------------------------------------------------------------------
__global__ __launch_bounds__(256, 4) void node_gemm(
    const float* __restrict__ z, const unsigned short* __restrict__ afw,
    const float* __restrict__ b1, unsigned short* __restrict__ h1ab) {
  const int l = threadIdx.x & 63, w = threadIdx.x >> 6;
  const int nh = w >> 1, fh = w & 1;       // node-half, feature-half
  const int wt = blockIdx.x * 2 + nh;      // node-group 0..6249
  if (wt >= NGT) return;
  const int c = l & 15, g = l >> 4;
  const int n0 = wt * 16;

  // z rows for this wave's 16 nodes, bf16-converted at load (16 VGPR)
  uint4 zlb[4];
#pragma unroll
  for (int kb = 0; kb < 4; kb++) {
    const float* zp = z + (n0 + c) * 128 + kb * 32 + g * 8;
    float4 a = *(const float4*)zp;
    float4 b = *(const float4*)(zp + 4);
    zlb[kb] = (uint4){pk2(a.x, a.y), pk2(a.z, a.w), pk2(b.x, b.y), pk2(b.z, b.w)};
  }

  f32x4 acc[8] = {};
#pragma unroll
  for (int kb = 0; kb < 4; kb++) {
    bf16x8 bfrag = __builtin_bit_cast(bf16x8, zlb[kb]);
#pragma unroll
    for (int mt = 0; mt < 8; mt++) {
      bf16x8 af = *(const bf16x8*)(afw + (((fh * 8 + mt) * 4 + kb) * 64 + l) * 8);
      acc[mt] = __builtin_amdgcn_mfma_f32_16x16x32_bf16(af, bfrag, acc[mt], 0, 0, 0);
    }
  }

  // epilogue: +b1 on features < 128 (fh==0 half), pack 4 bf16, 8 B store
#pragma unroll
  for (int mt = 0; mt < 8; mt++) {
    const int f0 = (fh * 8 + mt) * 16 + g * 4;
    float v0 = acc[mt][0], v1 = acc[mt][1], v2 = acc[mt][2], v3 = acc[mt][3];
    if (fh == 0) {
      float4 bb = *(const float4*)(b1 + f0);
      v0 += bb.x; v1 += bb.y; v2 += bb.z; v3 += bb.w;
    }
    uint2 pk = {pk2(v0, v1), pk2(v2, v3)};
    *(uint2*)(h1ab + (n0 + c) * 256 + f0) = pk;
  }
}

// ---------------------------------------------------------------------------
// Edge kernel — R8 structure (per-kb interleaved gathers, one 32-edge tile
// per wave, (256,6) occupancy). Nontemporal edge loads + out stores keep the
// streaming data out of L2/L3 so the h1ab gather retains more cache.
// ---------------------------------------------------------------------------
__global__ __launch_bounds__(256, 6) void mlp_edge(
    const unsigned short* __restrict__ h1ab, const int* __restrict__ edge,
    const unsigned short* __restrict__ fw2,
    const float* __restrict__ b2, const float* __restrict__ W3,
    const float* __restrict__ b3, float* __restrict__ out) {
  __shared__ __align__(16) unsigned short sfw2[8192];  // 16 KB
  {
    const int t = threadIdx.x;
#pragma unroll
    for (int st = 0; st < 4; st++)
      ((bf16x8*)sfw2)[st * 256 + t] = ((const bf16x8*)fw2)[st * 256 + t];
  }
  __syncthreads();  // before any wave can early-exit

  const int l = threadIdx.x & 63, w = threadIdx.x >> 6;
  const int wt = blockIdx.x * 4 + w;
  if (wt >= NWT) return;
  const int c = l & 15, g = l >> 4;
  const int eBase = wt * 32;

  const char* hb = (const char*)h1ab;
  const unsigned kbase = (unsigned)g * 16u;

  const int e0 = eBase + c;
  const int is0 = __builtin_nontemporal_load(edge + e0);
  const int is1 = __builtin_nontemporal_load(edge + e0 + 16);
  const int id0 = __builtin_nontemporal_load(edge + NE + e0);
  const int id1 = __builtin_nontemporal_load(edge + NE + e0 + 16);
  const unsigned so0 = (unsigned)is0 * 512u + kbase;
  const unsigned so1 = (unsigned)is1 * 512u + kbase;
  const unsigned do0 = (unsigned)id0 * 512u + 256u + kbase;
  const unsigned do1 = (unsigned)id1 * 512u + 256u + kbase;

  f32x4 acc2[2][4] = {};
#pragma unroll
  for (int kb = 0; kb < 4; kb++) {
    const unsigned o = (unsigned)kb * 64u;
    uint4 sv[2], dv[2];
    sv[0] = *(const uint4*)(hb + so0 + o);
    sv[1] = *(const uint4*)(hb + so1 + o);
    dv[0] = *(const uint4*)(hb + do0 + o);
    dv[1] = *(const uint4*)(hb + do1 + o);

    bf16x8 a2[2];
#pragma unroll
    for (int mt = 0; mt < 2; mt++) {
      uint4 s = sv[mt], d = dv[mt];
      uint4 r;
      r.x = pk2(fmaxf(lo2f(s.x) + lo2f(d.x), 0.f), fmaxf(hi2f(s.x) + hi2f(d.x), 0.f));
      r.y = pk2(fmaxf(lo2f(s.y) + lo2f(d.y), 0.f), fmaxf(hi2f(s.y) + hi2f(d.y), 0.f));
      r.z = pk2(fmaxf(lo2f(s.z) + lo2f(d.z), 0.f), fmaxf(hi2f(s.z) + hi2f(d.z), 0.f));
      r.w = pk2(fmaxf(lo2f(s.w) + lo2f(d.w), 0.f), fmaxf(hi2f(s.w) + hi2f(d.w), 0.f));
      a2[mt] = __builtin_bit_cast(bf16x8, r);
    }
#pragma unroll
    for (int nt = 0; nt < 4; nt++) {
      bf16x8 bf = ((const bf16x8*)sfw2)[(nt * 4 + kb) * 64 + l];
      acc2[0][nt] = __builtin_amdgcn_mfma_f32_16x16x32_bf16(a2[0], bf, acc2[0][nt], 0, 0, 0);
      acc2[1][nt] = __builtin_amdgcn_mfma_f32_16x16x32_bf16(a2[1], bf, acc2[1][nt], 0, 0, 0);
    }
  }

  // ---- Layer 3: relu(H2 + b2) . W3 + b3 ----
  float w3v[4], b2v[4];
#pragma unroll
  for (int nt = 0; nt < 4; nt++) {
    w3v[nt] = W3[nt * 16 + c];
    b2v[nt] = b2[nt * 16 + c];
  }
  const float bias3 = b3[0];
#pragma unroll
  for (int mt = 0; mt < 2; mt++) {
#pragma unroll
    for (int i = 0; i < 4; i++) {
      float t = 0.f;
#pragma unroll
      for (int nt = 0; nt < 4; nt++)
        t += fmaxf(acc2[mt][nt][i] + b2v[nt], 0.f) * w3v[nt];
      t += __shfl_xor(t, 1);
      t += __shfl_xor(t, 2);
      t += __shfl_xor(t, 4);
      t += __shfl_xor(t, 8);
      if (c == 0)
        __builtin_nontemporal_store(t + bias3, out + eBase + mt * 16 + g * 4 + i);
    }
  }
}

extern "C" void kernel_launch(void* const* d_in, const int* in_sizes, int n_in,
                              void* d_out, int out_size, void* d_ws, size_t ws_size,
                              hipStream_t stream) {
  const float* z  = (const float*)d_in[0];
  const int* edge = (const int*)d_in[1];   // jax x64 off -> int32
  const float* W1 = (const float*)d_in[2];
  const float* b1 = (const float*)d_in[3];
  const float* W2 = (const float*)d_in[4];
  const float* b2 = (const float*)d_in[5];
  const float* W3 = (const float*)d_in[6];
  const float* b3 = (const float*)d_in[7];
  float* out = (float*)d_out;

  unsigned short* afw  = (unsigned short*)d_ws;       // 64 KB  Wcat^T A-frags
  unsigned short* fw2  = afw + 32768;                 // 16 KB  W2 B-frags
  unsigned short* h1ab = fw2 + 8192;                  // 51.2 MB per-node partials

  prep<<<160, 256, 0, stream>>>(W1, W2, afw, fw2);
  node_gemm<<<NGT / 2, 256, 0, stream>>>(z, afw, b1, h1ab);  // 3125 blocks
  mlp_edge<<<(NWT + 3) / 4, 256, 0, stream>>>(h1ab, edge, fw2, b2, W3, b3, out);
}

// Round 12
// 196.964 us; speedup vs baseline: 1.0899x; 1.0899x over previous
//
#include <hip/hip_runtime.h>
#include <hip/hip_bf16.h>
#include <string.h>

#define NE 1000000
#define NN 100000
#define NWT 31250    // edges / 32 per wave-tile
#define NGT2 3125    // nodes / 32 per wave-tile (G=2 groups of 16)

typedef __attribute__((ext_vector_type(8))) short bf16x8;
typedef __attribute__((ext_vector_type(4))) float f32x4;

__device__ __forceinline__ unsigned short f2bf(float f) {
  // round-to-nearest-even f32 -> bf16 (prep only)
  unsigned u = __builtin_bit_cast(unsigned, f);
  u += 0x7fffu + ((u >> 16) & 1u);
  return (unsigned short)(u >> 16);
}
// packed pair: low16 = bf16(a), high16 = bf16(b)  (v_cvt_pk_bf16_f32)
__device__ __forceinline__ unsigned pk2(float a, float b) {
  __hip_bfloat162 h = __float22bfloat162_rn(make_float2(a, b));
  unsigned r;
  memcpy(&r, &h, 4);  // __hip_bfloat162 not trivially copyable -> no bit_cast
  return r;
}
__device__ __forceinline__ float lo2f(unsigned u) {
  return __builtin_bit_cast(float, u << 16);
}
__device__ __forceinline__ float hi2f(unsigned u) {
  return __builtin_bit_cast(float, u & 0xffff0000u);
}

// ---------------------------------------------------------------------------
// Prep: MFMA fragments for Wcat^T (A-operand of node_gemm) and W2 (B-operand
// of edge kernel). Wcat = [W1a | W1b] : [128][256].
// A-frag(mt,kb): lane l, j: Wcat[kb*32+(l>>4)*8+j][mt*16+(l&15)]  (16 mt, 4 kb)
// B-frag(nt,kb): lane l, j: W2[kb*32+(l>>4)*8+j][nt*16+(l&15)]    (4 nt, 4 kb)
// ---------------------------------------------------------------------------
__global__ void prep(const float* __restrict__ W1, const float* __restrict__ W2,
                     unsigned short* __restrict__ afw, unsigned short* __restrict__ fw2) {
  int tid = blockIdx.x * 256 + threadIdx.x;
  if (tid < 32768) {
    int j = tid & 7, l = (tid >> 3) & 63, kb = (tid >> 9) & 3, mt = tid >> 11;
    int k = kb * 32 + (l >> 4) * 8 + j;   // 0..127
    int n = mt * 16 + (l & 15);           // 0..255
    float v = (n < 128) ? W1[k * 128 + n] : W1[(128 + k) * 128 + (n - 128)];
    afw[tid] = f2bf(v);
  } else if (tid < 40960) {
    int t = tid - 32768;
    int j = t & 7, l = (t >> 3) & 63, kb = (t >> 9) & 3, nt = t >> 11;
    fw2[t] = f2bf(W2[(kb * 32 + (l >> 4) * 8 + j) * 64 + nt * 16 + (l & 15)]);
  }
}

// ---------------------------------------------------------------------------
// node_gemm (R8 structure, best measured): h1ab[n][0:128] = z[n]@W1a + b1,
// h1ab[n][128:256] = z[n]@W1b. Swapped-operand MFMA: A = Wcat^T frags
// (features), B = z rows (nodes). G=2 node-groups per wave (32 nodes) ->
// afw ds_read shared across both groups; afw staged in 64 KB LDS per block.
// R10 fix: z global loads issued BEFORE the staging loop so their HBM
// latency hides under the 16 staging loads + barrier. z converted to bf16
// at load (32 VGPR payload) so acc(128)+payload fits (256,2)'s 256-VGPR cap.
// ---------------------------------------------------------------------------
__global__ __launch_bounds__(256, 2) void node_gemm(
    const float* __restrict__ z, const unsigned short* __restrict__ afw,
    const float* __restrict__ b1, unsigned short* __restrict__ h1ab) {
  __shared__ __align__(16) bf16x8 sfw[4096];  // 64 KB
  const int l = threadIdx.x & 63, w = threadIdx.x >> 6;
  const int wt = blockIdx.x * 4 + w;
  const int c = l & 15, g = l >> 4;
  const int n0 = wt * 32;
  const bool active = (wt < NGT2);

  // issue z loads FIRST (overlap their latency with staging + barrier)
  uint4 zlb[2][4];
  if (active) {
#pragma unroll
    for (int grp = 0; grp < 2; grp++)
#pragma unroll
      for (int kb = 0; kb < 4; kb++) {
        const float* zp = z + (n0 + grp * 16 + c) * 128 + kb * 32 + g * 8;
        float4 a = *(const float4*)zp;
        float4 b = *(const float4*)(zp + 4);
        zlb[grp][kb] = (uint4){pk2(a.x, a.y), pk2(a.z, a.w), pk2(b.x, b.y), pk2(b.z, b.w)};
      }
  }

  {
    const int t = threadIdx.x;
#pragma unroll
    for (int it = 0; it < 16; it++)
      sfw[it * 256 + t] = ((const bf16x8*)afw)[it * 256 + t];
  }
  __syncthreads();
  if (!active) return;

  f32x4 acc[2][16] = {};
#pragma unroll
  for (int kb = 0; kb < 4; kb++) {
    bf16x8 bf0 = __builtin_bit_cast(bf16x8, zlb[0][kb]);
    bf16x8 bf1 = __builtin_bit_cast(bf16x8, zlb[1][kb]);
#pragma unroll
    for (int mt = 0; mt < 16; mt++) {
      bf16x8 af = sfw[(mt * 4 + kb) * 64 + l];
      acc[0][mt] = __builtin_amdgcn_mfma_f32_16x16x32_bf16(af, bf0, acc[0][mt], 0, 0, 0);
      acc[1][mt] = __builtin_amdgcn_mfma_f32_16x16x32_bf16(af, bf1, acc[1][mt], 0, 0, 0);
    }
  }

  // epilogue: +b1 on features < 128, pack 4 bf16, 8 B store per (grp, mt)
#pragma unroll
  for (int grp = 0; grp < 2; grp++)
#pragma unroll
    for (int mt = 0; mt < 16; mt++) {
      const int f0 = mt * 16 + g * 4;
      float v0 = acc[grp][mt][0], v1 = acc[grp][mt][1];
      float v2 = acc[grp][mt][2], v3 = acc[grp][mt][3];
      if (mt < 8) {
        float4 bb = *(const float4*)(b1 + f0);
        v0 += bb.x; v1 += bb.y; v2 += bb.z; v3 += bb.w;
      }
      uint2 pk = {pk2(v0, v1), pk2(v2, v3)};
      *(uint2*)(h1ab + (n0 + grp * 16 + c) * 256 + f0) = pk;
    }
}

// ---------------------------------------------------------------------------
// Edge kernel — R8 exact (best measured): per-kb interleaved gathers, one
// 32-edge tile per wave, (256,6). Plain (cached) loads/stores — R9 showed
// nontemporal stores 4x'd WRITE_SIZE (no L2 write-combining) and cost 5 us.
// ---------------------------------------------------------------------------
__global__ __launch_bounds__(256, 6) void mlp_edge(
    const unsigned short* __restrict__ h1ab, const int* __restrict__ edge,
    const unsigned short* __restrict__ fw2,
    const float* __restrict__ b2, const float* __restrict__ W3,
    const float* __restrict__ b3, float* __restrict__ out) {
  __shared__ __align__(16) unsigned short sfw2[8192];  // 16 KB
  {
    const int t = threadIdx.x;
#pragma unroll
    for (int st = 0; st < 4; st++)
      ((bf16x8*)sfw2)[st * 256 + t] = ((const bf16x8*)fw2)[st * 256 + t];
  }
  __syncthreads();  // before any wave can early-exit

  const int l = threadIdx.x & 63, w = threadIdx.x >> 6;
  const int wt = blockIdx.x * 4 + w;
  if (wt >= NWT) return;
  const int c = l & 15, g = l >> 4;
  const int eBase = wt * 32;

  const char* hb = (const char*)h1ab;
  const unsigned kbase = (unsigned)g * 16u;

  const int e0 = eBase + c;
  const unsigned so0 = (unsigned)edge[e0] * 512u + kbase;
  const unsigned so1 = (unsigned)edge[e0 + 16] * 512u + kbase;
  const unsigned do0 = (unsigned)edge[NE + e0] * 512u + 256u + kbase;
  const unsigned do1 = (unsigned)edge[NE + e0 + 16] * 512u + 256u + kbase;

  f32x4 acc2[2][4] = {};
#pragma unroll
  for (int kb = 0; kb < 4; kb++) {
    const unsigned o = (unsigned)kb * 64u;
    uint4 sv[2], dv[2];
    sv[0] = *(const uint4*)(hb + so0 + o);
    sv[1] = *(const uint4*)(hb + so1 + o);
    dv[0] = *(const uint4*)(hb + do0 + o);
    dv[1] = *(const uint4*)(hb + do1 + o);

    bf16x8 a2[2];
#pragma unroll
    for (int mt = 0; mt < 2; mt++) {
      uint4 s = sv[mt], d = dv[mt];
      uint4 r;
      r.x = pk2(fmaxf(lo2f(s.x) + lo2f(d.x), 0.f), fmaxf(hi2f(s.x) + hi2f(d.x), 0.f));
      r.y = pk2(fmaxf(lo2f(s.y) + lo2f(d.y), 0.f), fmaxf(hi2f(s.y) + hi2f(d.y), 0.f));
      r.z = pk2(fmaxf(lo2f(s.z) + lo2f(d.z), 0.f), fmaxf(hi2f(s.z) + hi2f(d.z), 0.f));
      r.w = pk2(fmaxf(lo2f(s.w) + lo2f(d.w), 0.f), fmaxf(hi2f(s.w) + hi2f(d.w), 0.f));
      a2[mt] = __builtin_bit_cast(bf16x8, r);
    }
#pragma unroll
    for (int nt = 0; nt < 4; nt++) {
      bf16x8 bf = ((const bf16x8*)sfw2)[(nt * 4 + kb) * 64 + l];
      acc2[0][nt] = __builtin_amdgcn_mfma_f32_16x16x32_bf16(a2[0], bf, acc2[0][nt], 0, 0, 0);
      acc2[1][nt] = __builtin_amdgcn_mfma_f32_16x16x32_bf16(a2[1], bf, acc2[1][nt], 0, 0, 0);
    }
  }

  // ---- Layer 3: relu(H2 + b2) . W3 + b3 ----
  float w3v[4], b2v[4];
#pragma unroll
  for (int nt = 0; nt < 4; nt++) {
    w3v[nt] = W3[nt * 16 + c];
    b2v[nt] = b2[nt * 16 + c];
  }
  const float bias3 = b3[0];
#pragma unroll
  for (int mt = 0; mt < 2; mt++) {
#pragma unroll
    for (int i = 0; i < 4; i++) {
      float t = 0.f;
#pragma unroll
      for (int nt = 0; nt < 4; nt++)
        t += fmaxf(acc2[mt][nt][i] + b2v[nt], 0.f) * w3v[nt];
      t += __shfl_xor(t, 1);
      t += __shfl_xor(t, 2);
      t += __shfl_xor(t, 4);
      t += __shfl_xor(t, 8);
      if (c == 0) out[eBase + mt * 16 + g * 4 + i] = t + bias3;
    }
  }
}

extern "C" void kernel_launch(void* const* d_in, const int* in_sizes, int n_in,
                              void* d_out, int out_size, void* d_ws, size_t ws_size,
                              hipStream_t stream) {
  const float* z  = (const float*)d_in[0];
  const int* edge = (const int*)d_in[1];   // jax x64 off -> int32
  const float* W1 = (const float*)d_in[2];
  const float* b1 = (const float*)d_in[3];
  const float* W2 = (const float*)d_in[4];
  const float* b2 = (const float*)d_in[5];
  const float* W3 = (const float*)d_in[6];
  const float* b3 = (const float*)d_in[7];
  float* out = (float*)d_out;

  unsigned short* afw  = (unsigned short*)d_ws;       // 64 KB  Wcat^T A-frags
  unsigned short* fw2  = afw + 32768;                 // 16 KB  W2 B-frags
  unsigned short* h1ab = fw2 + 8192;                  // 51.2 MB per-node partials

  prep<<<160, 256, 0, stream>>>(W1, W2, afw, fw2);
  node_gemm<<<(NGT2 + 3) / 4, 256, 0, stream>>>(z, afw, b1, h1ab);
  mlp_edge<<<(NWT + 3) / 4, 256, 0, stream>>>(h1ab, edge, fw2, b2, W3, b3, out);
}